// Round 19
// baseline (178.870 us; speedup 1.0000x reference)
//
#include <hip/hip_runtime.h>
#include <hip/hip_bf16.h>
#include <math.h>

typedef short bf16x8 __attribute__((ext_vector_type(8)));
typedef float f32x16 __attribute__((ext_vector_type(16)));
typedef float f32x4 __attribute__((ext_vector_type(4)));
typedef float f32x2 __attribute__((ext_vector_type(2)));
typedef unsigned u32x4 __attribute__((ext_vector_type(4)));
typedef unsigned u32x2 __attribute__((ext_vector_type(2)));
typedef unsigned uu2 __attribute__((ext_vector_type(2), aligned(4)));
typedef float ff4 __attribute__((ext_vector_type(4), aligned(8)));

#define NF 4
#define D0 8
#define LPE_OUT 24
#define NBUCKET 4096                    // 64 v-rows x 64 u-cols (fine buckets)
#define NROWS   512                     // hist/scatter chunks (2048 pts each)

// ---------------- ws byte layout ----------------
#define TOTC_OFF   17408ULL             // totals[4096] + cursor[4096] = 32 KB (one memset)
#define LPE_OFF    1068544ULL           // 16641 cells x 48 B bf16
#define SCOORD_OFF 1867776ULL           // sorted float2, 8 MB
#define PERM_OFF   10256384ULL          // u32 perm, 4 MB
#define G6B_OFF    14450688ULL          // 1024^2 u32 (bf16x2), 4 MB
#define G7B_OFF    18644992ULL          // 2048^2 u32 (bf16x2), 16 MB
#define WS_NEED    35422208ULL

// ---------- bf16 helpers ----------
__device__ __forceinline__ unsigned f2bf(float x) {           // manual RNE (prep only)
    unsigned u = __float_as_uint(x);
    u = u + 0x7fffu + ((u >> 16) & 1u);
    return u >> 16;
}
__device__ __forceinline__ unsigned pkbf(float a, float b) {
    __hip_bfloat16 ha = __float2bfloat16(a);
    __hip_bfloat16 hb = __float2bfloat16(b);
    unsigned short ua, ub;
    __builtin_memcpy(&ua, &ha, 2);
    __builtin_memcpy(&ub, &hb, 2);
    return (unsigned)ua | ((unsigned)ub << 16);
}
__device__ __forceinline__ float bflo(unsigned u) { return __uint_as_float(u << 16); }
__device__ __forceinline__ float bfhi(unsigned u) { return __uint_as_float(u & 0xffff0000u); }
__device__ __forceinline__ f32x2 bf2(unsigned u) { f32x2 r = { bflo(u), bfhi(u) }; return r; }
__device__ __forceinline__ bf16x8 mkfrag(unsigned w0, unsigned w1, unsigned w2, unsigned w3) {
    u32x4 u = { w0, w1, w2, w3 };
    return __builtin_bit_cast(bf16x8, u);
}

// ---------- weight prep body (R3..R18-verified) ----------
__device__ void prep_body(const float* __restrict__ w0, const float* __restrict__ b0,
                          const float* __restrict__ w1, const float* __restrict__ b1,
                          const float* __restrict__ w2, float* __restrict__ ws, int t)
{
    unsigned short* a0 = (unsigned short*)ws;
    unsigned short* a1 = a0 + 2048;
    unsigned short* a2 = a1 + 4096;
    float* b0c = (float*)(a2 + 2048);
    float* b1c = b0c + 64;

    for (int e = t; e < 2048; e += 256) {
        int tile = e >> 9, lane = (e >> 3) & 63, j = e & 7;
        int m = tile >> 1, ks = tile & 1;
        int row = m * 32 + (lane & 31);
        int k = ks * 16 + (lane >> 5) * 8 + j;
        float v = (k < 26) ? w0[k * 64 + row] : 0.f;
        a0[e] = (unsigned short)f2bf(v);
    }
    for (int e = t; e < 4096; e += 256) {
        int tile = e >> 9, lane = (e >> 3) & 63, j = e & 7;
        int m = tile >> 2, ks = tile & 3;
        int row = m * 32 + (lane & 31);
        int k = ks * 16 + (lane >> 5) * 8 + j;
        a1[e] = (unsigned short)f2bf(w1[k * 64 + row]);
    }
    for (int e = t; e < 2048; e += 256) {
        int ks = e >> 9, lane = (e >> 3) & 63, j = e & 7;
        int row = lane & 31;
        int k = ks * 16 + (lane >> 5) * 8 + j;
        float v = (row < 4) ? w2[k * 4 + row] : 0.f;
        a2[e] = (unsigned short)f2bf(v);
    }
    if (t < 64) {
        int m = t >> 5, q5 = (t >> 4) & 1, r = t & 15;
        int row = (r & 3) + 8 * (r >> 2) + 4 * q5;
        b0c[(m * 2 + q5) * 16 + r] = b0[m * 32 + row];
        b1c[(m * 2 + q5) * 16 + r] = b1[m * 32 + row];
    }
}

__global__ void prep_kernel(const float* __restrict__ w0, const float* __restrict__ b0,
                            const float* __restrict__ w1, const float* __restrict__ b1,
                            const float* __restrict__ w2, float* __restrict__ ws)
{
    prep_body(w0, b0, w1, b1, w2, ws, threadIdx.x);
}

__device__ __forceinline__ int bucket_of(float cx, float cy) {
    float u = fminf(fmaxf(cx, 0.f), 1.f - 1e-6f);
    float v = fminf(fmaxf(cy, 0.f), 1.f - 1e-6f);
    return (int)(v * 64.f) * 64 + (int)(u * 64.f);
}

// ---------- fused pre-pass: float4-wide g7/g6 conv + LPE conv + hist(4096) + prep ----------
// blocks: [0,8192) g7 | [8192,10240) g6 | [10240,10436) LPE | [10436,10948) hist | 10948 prep
__global__ __launch_bounds__(256)
void fused_pre(const float4* __restrict__ g6q, const float4* __restrict__ g7q,
               const float4* __restrict__ lpe4, const float2* __restrict__ coords,
               unsigned* __restrict__ totals,
               const float* __restrict__ w0, const float* __restrict__ b0,
               const float* __restrict__ w1, const float* __restrict__ b1,
               const float* __restrict__ w2, float* __restrict__ ws, char* __restrict__ wsb)
{
    int b = blockIdx.x, t = threadIdx.x;
    if (b < 8192) {
        int i = b * 256 + t;
        float4 f = g7q[i];
        u32x2 o = { pkbf(f.x, f.y), pkbf(f.z, f.w) };
        ((u32x2*)(wsb + G7B_OFF))[i] = o;
        return;
    }
    if (b < 10240) {
        int i = (b - 8192) * 256 + t;
        float4 f = g6q[i];
        u32x2 o = { pkbf(f.x, f.y), pkbf(f.z, f.w) };
        ((u32x2*)(wsb + G6B_OFF))[i] = o;
        return;
    }
    if (b < 10436) {
        int i = (b - 10240) * 256 + t;
        if (i < 49923) {
            float4 a = lpe4[i * 2], c = lpe4[i * 2 + 1];
            u32x4 o = { pkbf(a.x, a.y), pkbf(a.z, a.w), pkbf(c.x, c.y), pkbf(c.z, c.w) };
            ((u32x4*)(wsb + LPE_OFF))[i] = o;
        }
        return;
    }
    if (b < 10948) {
        int hb = b - 10436;
        __shared__ unsigned h[NBUCKET];
#pragma unroll
        for (int k = 0; k < 16; ++k) h[k * 256 + t] = 0;
        __syncthreads();
        for (int k = 0; k < 8; ++k) {
            float2 c = coords[hb * 2048 + k * 256 + t];
            atomicAdd(&h[bucket_of(c.x, c.y)], 1u);
        }
        __syncthreads();
#pragma unroll
        for (int k = 0; k < 16; ++k) {
            unsigned v = h[k * 256 + t];
            if (v) atomicAdd(&totals[k * 256 + t], v);
        }
        return;
    }
    prep_body(w0, b0, w1, b1, w2, ws, t);
}

// ---------- scatter: two-stage excl scan of totals[4096] + cursor-reserved ranges ----------
__global__ __launch_bounds__(256)
void sort_scatter(const float2* __restrict__ coords,
                  const unsigned* __restrict__ totals, unsigned* __restrict__ cursor,
                  float2* __restrict__ scoord, unsigned* __restrict__ perm)
{
    __shared__ unsigned cnt[NBUCKET];      // 16 KB
    __shared__ unsigned rnk[NBUCKET];      // 16 KB
    __shared__ unsigned basev[NBUCKET];    // 16 KB
    __shared__ unsigned red[256];
    int t = threadIdx.x, hb = blockIdx.x;

    // thread t owns buckets [16t, 16t+16)
    unsigned loc[16];
    unsigned s = 0;
#pragma unroll
    for (int k = 0; k < 16; ++k) {
        loc[k] = totals[16 * t + k];
        s += loc[k];
        cnt[16 * t + k] = 0;
        rnk[16 * t + k] = 0;
    }
    red[t] = s;
    __syncthreads();
    // inclusive Hillis-Steele over 256 partials
    for (int off = 1; off < 256; off <<= 1) {
        unsigned v = (t >= off) ? red[t - off] : 0u;
        __syncthreads();
        red[t] += v;
        __syncthreads();
    }
    unsigned excl = red[t] - s;            // exclusive start of this thread's range

    // count this block's 2048 points
    float2 cpt[8]; int bkt[8];
#pragma unroll
    for (int k = 0; k < 8; ++k) {
        cpt[k] = coords[hb * 2048 + k * 256 + t];
        bkt[k] = bucket_of(cpt[k].x, cpt[k].y);
        atomicAdd(&cnt[bkt[k]], 1u);
    }
    __syncthreads();

    // reserve ranges for this thread's 16 buckets
    unsigned run = excl;
#pragma unroll
    for (int k = 0; k < 16; ++k) {
        int bb = 16 * t + k;
        unsigned cb = cnt[bb];
        if (cb) basev[bb] = run + atomicAdd(&cursor[bb], cb);
        run += loc[k];
    }
    __syncthreads();

    // rank within block + write
#pragma unroll
    for (int k = 0; k < 8; ++k) {
        unsigned r = atomicAdd(&rnk[bkt[k]], 1u);
        unsigned slot = basev[bkt[k]] + r;
        scoord[slot] = cpt[k];
        perm[slot] = (unsigned)(hb * 2048 + k * 256 + t);
    }
}

// ================= shared MLP pipeline (R4..R18-verified math) =================
__device__ __forceinline__ void mlp_pair(const unsigned (&B0)[2][2][4],
                                         const float* __restrict__ ws,
                                         const float* __restrict__ b2,
                                         int lane, int q5, f32x16 (&acc2)[2])
{
    const bf16x8* A0 = (const bf16x8*)ws;
    const bf16x8* A1 = (const bf16x8*)((const char*)ws + 4096);
    const bf16x8* A2 = (const bf16x8*)((const char*)ws + 12288);
    const float4* b0c = (const float4*)((const char*)ws + 16384);
    const float4* b1c = (const float4*)((const char*)ws + 16640);

    unsigned B1[4][2][4];
#pragma unroll
    for (int m = 0; m < 2; ++m) {
        f32x16 acc[2];
#pragma unroll
        for (int cc = 0; cc < 4; ++cc) {
            float4 bq = b0c[(m * 2 + q5) * 4 + cc];
#pragma unroll
            for (int n = 0; n < 2; ++n) {
                acc[n][4 * cc + 0] = bq.x;
                acc[n][4 * cc + 1] = bq.y;
                acc[n][4 * cc + 2] = bq.z;
                acc[n][4 * cc + 3] = bq.w;
            }
        }
#pragma unroll
        for (int ks = 0; ks < 2; ++ks) {
            bf16x8 af = A0[(m * 2 + ks) * 64 + lane];
#pragma unroll
            for (int n = 0; n < 2; ++n)
                acc[n] = __builtin_amdgcn_mfma_f32_32x32x16_bf16(
                    af, mkfrag(B0[ks][n][0], B0[ks][n][1], B0[ks][n][2], B0[ks][n][3]),
                    acc[n], 0, 0, 0);
        }
#pragma unroll
        for (int t = 0; t < 2; ++t) {
#pragma unroll
            for (int n = 0; n < 2; ++n)
#pragma unroll
                for (int c = 0; c < 2; ++c) {
                    int r0 = 2 * c + 8 * t;
                    int r1 = 2 * c + 8 * t + 4;
                    unsigned P0 = pkbf(fmaxf(acc[n][r0], 0.f), fmaxf(acc[n][r0 + 1], 0.f));
                    unsigned P1 = pkbf(fmaxf(acc[n][r1], 0.f), fmaxf(acc[n][r1 + 1], 0.f));
                    auto r = __builtin_amdgcn_permlane32_swap(P1, P0, false, false);
                    B1[2 * m + t][n][c] = r[1];
                    B1[2 * m + t][n][2 + c] = r[0];
                }
        }
    }

    unsigned B2[4][2][4];
#pragma unroll
    for (int m = 0; m < 2; ++m) {
        f32x16 acc[2];
#pragma unroll
        for (int cc = 0; cc < 4; ++cc) {
            float4 bq = b1c[(m * 2 + q5) * 4 + cc];
#pragma unroll
            for (int n = 0; n < 2; ++n) {
                acc[n][4 * cc + 0] = bq.x;
                acc[n][4 * cc + 1] = bq.y;
                acc[n][4 * cc + 2] = bq.z;
                acc[n][4 * cc + 3] = bq.w;
            }
        }
#pragma unroll
        for (int ks = 0; ks < 4; ++ks) {
            bf16x8 af = A1[(m * 4 + ks) * 64 + lane];
#pragma unroll
            for (int n = 0; n < 2; ++n)
                acc[n] = __builtin_amdgcn_mfma_f32_32x32x16_bf16(
                    af, mkfrag(B1[ks][n][0], B1[ks][n][1], B1[ks][n][2], B1[ks][n][3]),
                    acc[n], 0, 0, 0);
        }
#pragma unroll
        for (int t = 0; t < 2; ++t) {
#pragma unroll
            for (int n = 0; n < 2; ++n)
#pragma unroll
                for (int c = 0; c < 2; ++c) {
                    int r0 = 2 * c + 8 * t;
                    int r1 = 2 * c + 8 * t + 4;
                    unsigned P0 = pkbf(fmaxf(acc[n][r0], 0.f), fmaxf(acc[n][r0 + 1], 0.f));
                    unsigned P1 = pkbf(fmaxf(acc[n][r1], 0.f), fmaxf(acc[n][r1 + 1], 0.f));
                    auto r = __builtin_amdgcn_permlane32_swap(P1, P0, false, false);
                    B2[2 * m + t][n][c] = r[1];
                    B2[2 * m + t][n][2 + c] = r[0];
                }
        }
    }

#pragma unroll
    for (int n = 0; n < 2; ++n)
#pragma unroll
        for (int r = 0; r < 16; ++r) acc2[n][r] = (r < 4) ? b2[r] : 0.f;
#pragma unroll
    for (int ks = 0; ks < 4; ++ks) {
        bf16x8 af = A2[ks * 64 + lane];
#pragma unroll
        for (int n = 0; n < 2; ++n)
            acc2[n] = __builtin_amdgcn_mfma_f32_32x32x16_bf16(
                af, mkfrag(B2[ks][n][0], B2[ks][n][1], B2[ks][n][2], B2[ks][n][3]),
                acc2[n], 0, 0, 0);
    }
}

// ---------- main sorted kernel (R18 body, unchanged) ----------
__global__ __launch_bounds__(256, 4)
void colornet_sorted(const float2* __restrict__ pts,
                     const unsigned* __restrict__ perm,
                     const float* __restrict__ g0, const float* __restrict__ g1,
                     const float* __restrict__ g2, const float* __restrict__ g3,
                     const float* __restrict__ g4, const float* __restrict__ g5,
                     const float* __restrict__ ws,
                     const float* __restrict__ b2,
                     f32x4* __restrict__ out)
{
    const int lane = threadIdx.x & 63;
    const int wave = threadIdx.x >> 6;
    const int q5 = lane >> 5;
    int bid = blockIdx.x;
    int cpx = gridDim.x >> 3;
    bid = (bid & 7) * cpx + (bid >> 3);     // XCD-chunk swizzle (grid % 8 == 0)
    const int base_pt = bid * 256 + wave * 64;
    const char* wsb = (const char*)ws;

    float2 c = pts[base_pt + lane];
    float uA = fminf(fmaxf(c.x, 0.f), 1.f - 1e-6f);
    float vA = fminf(fmaxf(c.y, 0.f), 1.f - 1e-6f);

#define ADDR(IDX, R) int gx##IDX; float lu##IDX, lv##IDX; \
    { float fu_ = uA * (float)((R) - 1), fv_ = vA * (float)((R) - 1); \
      int i0_ = (int)floorf(fu_), j0_ = (int)floorf(fv_); \
      i0_ = i0_ < 0 ? 0 : (i0_ > (R) - 2 ? (R) - 2 : i0_); \
      j0_ = j0_ < 0 ? 0 : (j0_ > (R) - 2 ? (R) - 2 : j0_); \
      lu##IDX = fu_ - (float)i0_; lv##IDX = fv_ - (float)j0_; \
      gx##IDX = i0_ + j0_ * (R); }
    ADDR(7, 2048) ADDR(6, 1024) ADDR(5, 512) ADDR(4, 256)
    ADDR(3, 128)  ADDR(2, 64)   ADDR(1, 32)  ADDR(0, 16)

    const unsigned* G7 = (const unsigned*)(wsb + G7B_OFF);
    const unsigned* G6 = (const unsigned*)(wsb + G6B_OFF);
    uu2 p7a = *(const uu2*)(G7 + gx7);
    uu2 p7b = *(const uu2*)(G7 + gx7 + 2048);
    uu2 p6a = *(const uu2*)(G6 + gx6);
    uu2 p6b = *(const uu2*)(G6 + gx6 + 1024);
    unsigned t7_0 = p7a[0], t7_1 = p7a[1], t7_2 = p7b[0], t7_3 = p7b[1];
    unsigned t6_0 = p6a[0], t6_1 = p6a[1], t6_2 = p6b[0], t6_3 = p6b[1];

#define LOADF(IDX, R, G) \
    ff4 fq##IDX##a = *(const ff4*)((G) + 2 * gx##IDX); \
    ff4 fq##IDX##b = *(const ff4*)((G) + 2 * (gx##IDX + (R))); \
    f32x2 f##IDX##_0 = { fq##IDX##a[0], fq##IDX##a[1] }, \
          f##IDX##_1 = { fq##IDX##a[2], fq##IDX##a[3] }, \
          f##IDX##_2 = { fq##IDX##b[0], fq##IDX##b[1] }, \
          f##IDX##_3 = { fq##IDX##b[2], fq##IDX##b[3] };
    LOADF(5, 512, g5) LOADF(4, 256, g4) LOADF(3, 128, g3)
    LOADF(2, 64,  g2) LOADF(1, 32,  g1) LOADF(0, 16,  g0)

    float lu_pe, lv_pe;
    int lc;
    {
        float fu = uA * 128.f, fv = vA * 128.f;
        int i0 = (int)floorf(fu);
        int j0 = (int)floorf(fv);
        i0 = i0 < 0 ? 0 : (i0 > 127 ? 127 : i0);
        j0 = j0 < 0 ? 0 : (j0 > 127 ? 127 : j0);
        lu_pe = fu - (float)i0;
        lv_pe = fv - (float)j0;
        lc = (i0 + j0 * 129) * 3;
    }
    const u32x4* LP = (const u32x4*)(wsb + LPE_OFF);
    u32x4 L00a = LP[lc],       L00b = LP[lc + 1],   L00c = LP[lc + 2];
    u32x4 L10a = LP[lc + 3],   L10b = LP[lc + 4],   L10c = LP[lc + 5];
    u32x4 L01a = LP[lc + 387], L01b = LP[lc + 388], L01c = LP[lc + 389];
    u32x4 L11a = LP[lc + 390], L11b = LP[lc + 391], L11c = LP[lc + 392];

    float pe[16];
#pragma unroll
    for (int kf = 0; kf < NF; ++kf) {
        float au = lu_pe * (float)(1 << kf);
        float av = lv_pe * (float)(1 << kf);
        float fu_ = __builtin_amdgcn_fractf(au);
        float fv_ = __builtin_amdgcn_fractf(av);
        pe[kf]          = __builtin_amdgcn_cosf(fu_);
        pe[NF + kf]     = __builtin_amdgcn_sinf(fu_);
        pe[2 * NF + kf] = __builtin_amdgcn_cosf(fv_);
        pe[3 * NF + kf] = __builtin_amdgcn_sinf(fv_);
    }

    f32x2 eA = { 0.f, 0.f };
#define WGT(IDX) float omu##IDX = 1.f - lu##IDX, omv##IDX = 1.f - lv##IDX; \
    float w00##IDX = omu##IDX * omv##IDX, w10##IDX = lu##IDX * omv##IDX, \
          w01##IDX = omu##IDX * lv##IDX,  w11##IDX = lu##IDX * lv##IDX;
    { WGT(7)
      eA += bf2(t7_0) * w007 + bf2(t7_1) * w107 + bf2(t7_2) * w017 + bf2(t7_3) * w117; }
    { WGT(6)
      eA += bf2(t6_0) * w006 + bf2(t6_1) * w106 + bf2(t6_2) * w016 + bf2(t6_3) * w116; }
#define SUMF(IDX) { WGT(IDX) \
      eA += f##IDX##_0 * w00##IDX + f##IDX##_1 * w10##IDX + f##IDX##_2 * w01##IDX + f##IDX##_3 * w11##IDX; }
    SUMF(5) SUMF(4) SUMF(3) SUMF(2) SUMF(1) SUMF(0)

    f32x2 cf[12];
    {
        float omu = 1.f - lu_pe, omv = 1.f - lv_pe;
        float q00 = omu * omv, q10 = lu_pe * omv, q01 = omu * lv_pe, q11 = lu_pe * lv_pe;
#define LPW2(W, A, B, C, Dd) \
        cf[W] = bf2(A) * q00 + bf2(B) * q10 + bf2(C) * q01 + bf2(Dd) * q11;
        LPW2(0,  L00a[0], L10a[0], L01a[0], L11a[0])
        LPW2(1,  L00a[1], L10a[1], L01a[1], L11a[1])
        LPW2(2,  L00a[2], L10a[2], L01a[2], L11a[2])
        LPW2(3,  L00a[3], L10a[3], L01a[3], L11a[3])
        LPW2(4,  L00b[0], L10b[0], L01b[0], L11b[0])
        LPW2(5,  L00b[1], L10b[1], L01b[1], L11b[1])
        LPW2(6,  L00b[2], L10b[2], L01b[2], L11b[2])
        LPW2(7,  L00b[3], L10b[3], L01b[3], L11b[3])
        LPW2(8,  L00c[0], L10c[0], L01c[0], L11c[0])
        LPW2(9,  L00c[1], L10c[1], L01c[1], L11c[1])
        LPW2(10, L00c[2], L10c[2], L01c[2], L11c[2])
        LPW2(11, L00c[3], L10c[3], L01c[3], L11c[3])
#undef LPW2
    }

    unsigned fdA[16];
    fdA[0] = pkbf(eA[0], eA[1]);
#pragma unroll
    for (int i = 0; i < 4; ++i) fdA[1 + i] = pkbf(cf[i][0], cf[i][1]);
#pragma unroll
    for (int i = 0; i < 8; ++i) {
        f32x2 g = { pe[2 * i], pe[2 * i + 1] };
        f32x2 m = cf[4 + i] * g;
        fdA[5 + i] = pkbf(m[0], m[1]);
    }
    fdA[13] = 0u; fdA[14] = 0u; fdA[15] = 0u;

    unsigned B0a[2][2][4];
#pragma unroll
    for (int ks = 0; ks < 2; ++ks)
#pragma unroll
        for (int j2 = 0; j2 < 4; ++j2) {
            unsigned a = fdA[8 * ks + j2];
            unsigned b = fdA[8 * ks + 4 + j2];
            auto r = __builtin_amdgcn_permlane32_swap(b, a, false, false);
            B0a[ks][1][j2] = r[0];
            B0a[ks][0][j2] = r[1];
        }

    f32x16 acc2[2];
    mlp_pair(B0a, ws, b2, lane, q5, acc2);

    if (lane < 32) {
#pragma unroll
        for (int n = 0; n < 2; ++n) {
            f32x4 o;
            o[0] = 1.f / (1.f + __expf(-acc2[n][0]));
            o[1] = 1.f / (1.f + __expf(-acc2[n][1]));
            o[2] = 1.f / (1.f + __expf(-acc2[n][2]));
            o[3] = 1.f / (1.f + __expf(-acc2[n][3]));
            int oi = (int)perm[base_pt + 32 * n + lane];
            __builtin_nontemporal_store(o, out + oi);
        }
    }
}

// ---------- fp32 unsorted fallback (R6..R18-verified) ----------
template<int R>
__device__ __forceinline__ void gather_level(const float* __restrict__ g,
                                             float u, float v,
                                             float& e0, float& e1) {
    const float scale = (float)(R - 1);
    float fu = u * scale, fv = v * scale;
    int i0 = (int)floorf(fu);
    int j0 = (int)floorf(fv);
    i0 = i0 < 0 ? 0 : (i0 > R - 2 ? R - 2 : i0);
    j0 = j0 < 0 ? 0 : (j0 > R - 2 ? R - 2 : j0);
    float lu = fu - (float)i0;
    float lv = fv - (float)j0;
    const float2* gg = (const float2*)g;
    int base = i0 + j0 * R;
    float2 f00 = gg[base];
    float2 f10 = gg[base + 1];
    float2 f01 = gg[base + R];
    float2 f11 = gg[base + R + 1];
    float omu = 1.f - lu, omv = 1.f - lv;
    float w00 = omu * omv, w10 = lu * omv, w01 = omu * lv, w11 = lu * lv;
    e0 += f00.x * w00 + f10.x * w10 + f01.x * w01 + f11.x * w11;
    e1 += f00.y * w00 + f10.y * w10 + f01.y * w01 + f11.y * w11;
}

__global__ __launch_bounds__(256, 4)
void colornet_fp32(const float* __restrict__ coords,
                   const float* __restrict__ g0, const float* __restrict__ g1,
                   const float* __restrict__ g2, const float* __restrict__ g3,
                   const float* __restrict__ g4, const float* __restrict__ g5,
                   const float* __restrict__ g6, const float* __restrict__ g7,
                   const float* __restrict__ lpe,
                   const float* __restrict__ ws,
                   const float* __restrict__ b2,
                   f32x4* __restrict__ out)
{
    const int lane = threadIdx.x & 63;
    const int wave = threadIdx.x >> 6;
    const int q5 = lane >> 5;
    const int base_pt = blockIdx.x * 256 + wave * 64;
    const int point = base_pt + lane;

    const float* cp = coords + 2 * point;
    float cx = __builtin_nontemporal_load(cp);
    float cy = __builtin_nontemporal_load(cp + 1);
    float uA = fminf(fmaxf(cx, 0.f), 1.f - 1e-6f);
    float vA = fminf(fmaxf(cy, 0.f), 1.f - 1e-6f);

    float e0 = 0.f, e1 = 0.f;
    gather_level<16>(g0, uA, vA, e0, e1);
    gather_level<32>(g1, uA, vA, e0, e1);
    gather_level<64>(g2, uA, vA, e0, e1);
    gather_level<128>(g3, uA, vA, e0, e1);
    gather_level<256>(g4, uA, vA, e0, e1);
    gather_level<512>(g5, uA, vA, e0, e1);
    gather_level<1024>(g6, uA, vA, e0, e1);
    gather_level<2048>(g7, uA, vA, e0, e1);

    float coeff[LPE_OUT];
    float lu_pe, lv_pe;
    {
        float fu = uA * 128.f, fv = vA * 128.f;
        int i0 = (int)floorf(fu);
        int j0 = (int)floorf(fv);
        i0 = i0 < 0 ? 0 : (i0 > 127 ? 127 : i0);
        j0 = j0 < 0 ? 0 : (j0 > 127 ? 127 : j0);
        lu_pe = fu - (float)i0;
        lv_pe = fv - (float)j0;
        int base = (i0 + j0 * 129) * LPE_OUT;
        const float4* p00 = (const float4*)(lpe + base);
        const float4* p10 = (const float4*)(lpe + base + LPE_OUT);
        const float4* p01 = (const float4*)(lpe + base + 129 * LPE_OUT);
        const float4* p11 = (const float4*)(lpe + base + 130 * LPE_OUT);
        float omu = 1.f - lu_pe, omv = 1.f - lv_pe;
        float w00 = omu * omv, w10 = lu_pe * omv, w01 = omu * lv_pe, w11 = lu_pe * lv_pe;
#pragma unroll
        for (int q = 0; q < 6; ++q) {
            float4 a = p00[q], bq = p10[q], cq = p01[q], dq = p11[q];
            coeff[4 * q + 0] = a.x * w00 + bq.x * w10 + cq.x * w01 + dq.x * w11;
            coeff[4 * q + 1] = a.y * w00 + bq.y * w10 + cq.y * w01 + dq.y * w11;
            coeff[4 * q + 2] = a.z * w00 + bq.z * w10 + cq.z * w01 + dq.z * w11;
            coeff[4 * q + 3] = a.w * w00 + bq.w * w10 + cq.w * w01 + dq.w * w11;
        }
    }

    float pe[16];
#pragma unroll
    for (int kf = 0; kf < NF; ++kf) {
        const float fr = 6.28318530717958647692f * (float)(1 << kf);
        float au = lu_pe * fr;
        float av = lv_pe * fr;
        pe[kf]          = __cosf(au);
        pe[NF + kf]     = __sinf(au);
        pe[2 * NF + kf] = __cosf(av);
        pe[3 * NF + kf] = __sinf(av);
    }

    float feat[32];
    feat[0] = e0; feat[1] = e1;
#pragma unroll
    for (int q = 0; q < D0; ++q) feat[2 + q] = coeff[q];
#pragma unroll
    for (int q = 0; q < 4 * NF; ++q) feat[2 + D0 + q] = coeff[D0 + q] * pe[q];
#pragma unroll
    for (int q = 26; q < 32; ++q) feat[q] = 0.f;

    unsigned fd[16];
#pragma unroll
    for (int i = 0; i < 16; ++i) fd[i] = pkbf(feat[2 * i], feat[2 * i + 1]);

    unsigned B0[2][2][4];
#pragma unroll
    for (int ks = 0; ks < 2; ++ks)
#pragma unroll
        for (int j2 = 0; j2 < 4; ++j2) {
            unsigned a = fd[8 * ks + j2];
            unsigned b = fd[8 * ks + 4 + j2];
            auto r = __builtin_amdgcn_permlane32_swap(b, a, false, false);
            B0[ks][1][j2] = r[0];
            B0[ks][0][j2] = r[1];
        }

    f32x16 acc2[2];
    mlp_pair(B0, ws, b2, lane, q5, acc2);
    if (lane < 32) {
#pragma unroll
        for (int n = 0; n < 2; ++n) {
            f32x4 o;
            o[0] = 1.f / (1.f + __expf(-acc2[n][0]));
            o[1] = 1.f / (1.f + __expf(-acc2[n][1]));
            o[2] = 1.f / (1.f + __expf(-acc2[n][2]));
            o[3] = 1.f / (1.f + __expf(-acc2[n][3]));
            __builtin_nontemporal_store(o, out + (base_pt + 32 * n + lane));
        }
    }
}

extern "C" void kernel_launch(void* const* d_in, const int* in_sizes, int n_in,
                              void* d_out, int out_size, void* d_ws, size_t ws_size,
                              hipStream_t stream) {
    const float* coords = (const float*)d_in[0];
    const float* g0 = (const float*)d_in[1];
    const float* g1 = (const float*)d_in[2];
    const float* g2 = (const float*)d_in[3];
    const float* g3 = (const float*)d_in[4];
    const float* g4 = (const float*)d_in[5];
    const float* g5 = (const float*)d_in[6];
    const float* g6 = (const float*)d_in[7];
    const float* g7 = (const float*)d_in[8];
    const float* lpe = (const float*)d_in[9];
    const float* w0 = (const float*)d_in[10];
    const float* b0 = (const float*)d_in[11];
    const float* w1 = (const float*)d_in[12];
    const float* b1 = (const float*)d_in[13];
    const float* w2 = (const float*)d_in[14];
    const float* b2 = (const float*)d_in[15];
    f32x4* out = (f32x4*)d_out;

    int B = in_sizes[0] / 2;
    char* wsb = (char*)d_ws;

    if (ws_size >= WS_NEED && B == 1048576) {
        unsigned* totals = (unsigned*)(wsb + TOTC_OFF);
        unsigned* cursor = totals + NBUCKET;
        float2*   scoord = (float2*)(wsb + SCOORD_OFF);
        unsigned* perm   = (unsigned*)(wsb + PERM_OFF);
        const float2* c2 = (const float2*)coords;

        (void)hipMemsetAsync(totals, 0, 2 * NBUCKET * sizeof(unsigned), stream);
        fused_pre<<<10949, 256, 0, stream>>>((const float4*)g6, (const float4*)g7,
                                             (const float4*)lpe, c2, totals,
                                             w0, b0, w1, b1, w2, (float*)d_ws, wsb);
        sort_scatter<<<NROWS, 256, 0, stream>>>(c2, totals, cursor, scoord, perm);

        colornet_sorted<<<4096, 256, 0, stream>>>(scoord, perm,
                                                  g0, g1, g2, g3, g4, g5,
                                                  (const float*)d_ws, b2, out);
    } else {
        prep_kernel<<<1, 256, 0, stream>>>(w0, b0, w1, b1, w2, (float*)d_ws);
        colornet_fp32<<<B / 256, 256, 0, stream>>>(coords, g0, g1, g2, g3, g4, g5, g6, g7,
                                                   lpe, (const float*)d_ws, b2, out);
    }
}

// Round 20
// 118.670 us; speedup vs baseline: 1.5073x; 1.5073x over previous
//
#include <hip/hip_runtime.h>
#include <hip/hip_bf16.h>
#include <math.h>

typedef short bf16x8 __attribute__((ext_vector_type(8)));
typedef float f32x16 __attribute__((ext_vector_type(16)));
typedef float f32x4 __attribute__((ext_vector_type(4)));
typedef float f32x2 __attribute__((ext_vector_type(2)));
typedef unsigned u32x4 __attribute__((ext_vector_type(4)));
typedef unsigned u32x2 __attribute__((ext_vector_type(2)));

#define NF 4
#define D0 8
#define LPE_OUT 24
#define NBUCKET 512                     // 32 v-rows x 16 u-cols
#define NROWS   512                     // hist/scatter chunks (2048 pts each)

// ---------------- ws byte layout (R14..R17) ----------------
#define TOTC_OFF   17408ULL             // totals[512] + cursor[512] = 4 KB (one memset)
#define LPE_OFF    1068544ULL           // 16641 cells x 48 B bf16
#define SCOORD_OFF 1867776ULL           // sorted float2, 8 MB
#define PERM_OFF   10256384ULL          // u32 perm, 4 MB
#define G6B_OFF    14450688ULL          // 1024^2 u32 (bf16x2), 4 MB
#define G7B_OFF    18644992ULL          // 2048^2 u32 (bf16x2), 16 MB
#define WS_NEED    35422208ULL

// ---------- bf16 helpers ----------
__device__ __forceinline__ unsigned f2bf(float x) {           // manual RNE (prep only)
    unsigned u = __float_as_uint(x);
    u = u + 0x7fffu + ((u >> 16) & 1u);
    return u >> 16;
}
// fast pair-pack: v_cvt_pk path via hip casts (R12..R18-verified, absmax 0)
__device__ __forceinline__ unsigned pkbf(float a, float b) {
    __hip_bfloat16 ha = __float2bfloat16(a);
    __hip_bfloat16 hb = __float2bfloat16(b);
    unsigned short ua, ub;
    __builtin_memcpy(&ua, &ha, 2);
    __builtin_memcpy(&ub, &hb, 2);
    return (unsigned)ua | ((unsigned)ub << 16);
}
__device__ __forceinline__ float bflo(unsigned u) { return __uint_as_float(u << 16); }
__device__ __forceinline__ float bfhi(unsigned u) { return __uint_as_float(u & 0xffff0000u); }
__device__ __forceinline__ f32x2 bf2(unsigned u) { f32x2 r = { bflo(u), bfhi(u) }; return r; }
__device__ __forceinline__ bf16x8 mkfrag(unsigned w0, unsigned w1, unsigned w2, unsigned w3) {
    u32x4 u = { w0, w1, w2, w3 };
    return __builtin_bit_cast(bf16x8, u);
}

// ---------- weight prep body (R3..R18-verified) ----------
__device__ void prep_body(const float* __restrict__ w0, const float* __restrict__ b0,
                          const float* __restrict__ w1, const float* __restrict__ b1,
                          const float* __restrict__ w2, float* __restrict__ ws, int t)
{
    unsigned short* a0 = (unsigned short*)ws;
    unsigned short* a1 = a0 + 2048;
    unsigned short* a2 = a1 + 4096;
    float* b0c = (float*)(a2 + 2048);
    float* b1c = b0c + 64;

    for (int e = t; e < 2048; e += 256) {
        int tile = e >> 9, lane = (e >> 3) & 63, j = e & 7;
        int m = tile >> 1, ks = tile & 1;
        int row = m * 32 + (lane & 31);
        int k = ks * 16 + (lane >> 5) * 8 + j;
        float v = (k < 26) ? w0[k * 64 + row] : 0.f;
        a0[e] = (unsigned short)f2bf(v);
    }
    for (int e = t; e < 4096; e += 256) {
        int tile = e >> 9, lane = (e >> 3) & 63, j = e & 7;
        int m = tile >> 2, ks = tile & 3;
        int row = m * 32 + (lane & 31);
        int k = ks * 16 + (lane >> 5) * 8 + j;
        a1[e] = (unsigned short)f2bf(w1[k * 64 + row]);
    }
    for (int e = t; e < 2048; e += 256) {
        int ks = e >> 9, lane = (e >> 3) & 63, j = e & 7;
        int row = lane & 31;
        int k = ks * 16 + (lane >> 5) * 8 + j;
        float v = (row < 4) ? w2[k * 4 + row] : 0.f;
        a2[e] = (unsigned short)f2bf(v);
    }
    if (t < 64) {
        int m = t >> 5, q5 = (t >> 4) & 1, r = t & 15;
        int row = (r & 3) + 8 * (r >> 2) + 4 * q5;
        b0c[(m * 2 + q5) * 16 + r] = b0[m * 32 + row];
        b1c[(m * 2 + q5) * 16 + r] = b1[m * 32 + row];
    }
}

__global__ void prep_kernel(const float* __restrict__ w0, const float* __restrict__ b0,
                            const float* __restrict__ w1, const float* __restrict__ b1,
                            const float* __restrict__ w2, float* __restrict__ ws)
{
    prep_body(w0, b0, w1, b1, w2, ws, threadIdx.x);
}

__device__ __forceinline__ int bucket_of(float cx, float cy) {
    float u = fminf(fmaxf(cx, 0.f), 1.f - 1e-6f);
    float v = fminf(fmaxf(cy, 0.f), 1.f - 1e-6f);
    return (int)(v * 32.f) * 16 + (int)(u * 16.f);
}

// ---------- fused pre-pass: float4-wide g7/g6 conv + LPE conv + hist + prep (R15/R17) ----------
// blocks: [0,8192) g7 | [8192,10240) g6 | [10240,10436) LPE | [10436,10948) hist | 10948 prep
__global__ __launch_bounds__(256)
void fused_pre(const float4* __restrict__ g6q, const float4* __restrict__ g7q,
               const float4* __restrict__ lpe4, const float2* __restrict__ coords,
               unsigned* __restrict__ totals,
               const float* __restrict__ w0, const float* __restrict__ b0,
               const float* __restrict__ w1, const float* __restrict__ b1,
               const float* __restrict__ w2, float* __restrict__ ws, char* __restrict__ wsb)
{
    int b = blockIdx.x, t = threadIdx.x;
    if (b < 8192) {
        int i = b * 256 + t;                 // i indexes pairs of cells
        float4 f = g7q[i];
        u32x2 o = { pkbf(f.x, f.y), pkbf(f.z, f.w) };
        ((u32x2*)(wsb + G7B_OFF))[i] = o;
        return;
    }
    if (b < 10240) {
        int i = (b - 8192) * 256 + t;
        float4 f = g6q[i];
        u32x2 o = { pkbf(f.x, f.y), pkbf(f.z, f.w) };
        ((u32x2*)(wsb + G6B_OFF))[i] = o;
        return;
    }
    if (b < 10436) {
        int i = (b - 10240) * 256 + t;
        if (i < 49923) {
            float4 a = lpe4[i * 2], c = lpe4[i * 2 + 1];
            u32x4 o = { pkbf(a.x, a.y), pkbf(a.z, a.w), pkbf(c.x, c.y), pkbf(c.z, c.w) };
            ((u32x4*)(wsb + LPE_OFF))[i] = o;
        }
        return;
    }
    if (b < 10948) {
        int hb = b - 10436;
        __shared__ unsigned h[NBUCKET];
        h[t] = 0; h[t + 256] = 0;
        __syncthreads();
        for (int k = 0; k < 8; ++k) {
            float2 c = coords[hb * 2048 + k * 256 + t];
            atomicAdd(&h[bucket_of(c.x, c.y)], 1u);
        }
        __syncthreads();
        unsigned v0 = h[t], v1 = h[t + 256];
        if (v0) atomicAdd(&totals[t], v0);
        if (v1) atomicAdd(&totals[t + 256], v1);
        return;
    }
    prep_body(w0, b0, w1, b1, w2, ws, t);
}

// ---------- scatter: in-LDS prefix of totals + cursor-reserved ranges (R14..R17-verified) ----------
__global__ __launch_bounds__(256)
void sort_scatter(const float2* __restrict__ coords,
                  const unsigned* __restrict__ totals, unsigned* __restrict__ cursor,
                  float2* __restrict__ scoord, unsigned* __restrict__ perm)
{
    __shared__ unsigned ps[NBUCKET];
    __shared__ unsigned cnt[NBUCKET];
    __shared__ unsigned rnk[NBUCKET];
    __shared__ unsigned basev[NBUCKET];
    int t = threadIdx.x, hb = blockIdx.x;

    unsigned o0 = totals[t], o1 = totals[t + 256];
    ps[t] = o0; ps[t + 256] = o1;
    cnt[t] = 0; cnt[t + 256] = 0;
    rnk[t] = 0; rnk[t + 256] = 0;
    __syncthreads();
    for (int off = 1; off < 512; off <<= 1) {
        unsigned v0 = (t >= off) ? ps[t - off] : 0u;
        unsigned v1 = (t + 256 >= off) ? ps[t + 256 - off] : 0u;
        __syncthreads();
        ps[t] += v0; ps[t + 256] += v1;
        __syncthreads();
    }

    float2 cpt[8]; int bkt[8];
#pragma unroll
    for (int k = 0; k < 8; ++k) {
        cpt[k] = coords[hb * 2048 + k * 256 + t];
        bkt[k] = bucket_of(cpt[k].x, cpt[k].y);
        atomicAdd(&cnt[bkt[k]], 1u);
    }
    __syncthreads();

    unsigned c0 = cnt[t], c1 = cnt[t + 256];
    if (c0) basev[t]       = (ps[t] - o0)       + atomicAdd(&cursor[t], c0);
    if (c1) basev[t + 256] = (ps[t + 256] - o1) + atomicAdd(&cursor[t + 256], c1);
    __syncthreads();

#pragma unroll
    for (int k = 0; k < 8; ++k) {
        unsigned r = atomicAdd(&rnk[bkt[k]], 1u);
        unsigned slot = basev[bkt[k]] + r;
        scoord[slot] = cpt[k];
        perm[slot] = (unsigned)(hb * 2048 + k * 256 + t);
    }
}

// ================= shared MLP pipeline (R4..R18-verified math) =================
__device__ __forceinline__ void mlp_pair(const unsigned (&B0)[2][2][4],
                                         const float* __restrict__ ws,
                                         const float* __restrict__ b2,
                                         int lane, int q5, f32x16 (&acc2)[2])
{
    const bf16x8* A0 = (const bf16x8*)ws;
    const bf16x8* A1 = (const bf16x8*)((const char*)ws + 4096);
    const bf16x8* A2 = (const bf16x8*)((const char*)ws + 12288);
    const float4* b0c = (const float4*)((const char*)ws + 16384);
    const float4* b1c = (const float4*)((const char*)ws + 16640);

    unsigned B1[4][2][4];
#pragma unroll
    for (int m = 0; m < 2; ++m) {
        f32x16 acc[2];
#pragma unroll
        for (int cc = 0; cc < 4; ++cc) {
            float4 bq = b0c[(m * 2 + q5) * 4 + cc];
#pragma unroll
            for (int n = 0; n < 2; ++n) {
                acc[n][4 * cc + 0] = bq.x;
                acc[n][4 * cc + 1] = bq.y;
                acc[n][4 * cc + 2] = bq.z;
                acc[n][4 * cc + 3] = bq.w;
            }
        }
#pragma unroll
        for (int ks = 0; ks < 2; ++ks) {
            bf16x8 af = A0[(m * 2 + ks) * 64 + lane];
#pragma unroll
            for (int n = 0; n < 2; ++n)
                acc[n] = __builtin_amdgcn_mfma_f32_32x32x16_bf16(
                    af, mkfrag(B0[ks][n][0], B0[ks][n][1], B0[ks][n][2], B0[ks][n][3]),
                    acc[n], 0, 0, 0);
        }
#pragma unroll
        for (int t = 0; t < 2; ++t) {
#pragma unroll
            for (int n = 0; n < 2; ++n)
#pragma unroll
                for (int c = 0; c < 2; ++c) {
                    int r0 = 2 * c + 8 * t;
                    int r1 = 2 * c + 8 * t + 4;
                    unsigned P0 = pkbf(fmaxf(acc[n][r0], 0.f), fmaxf(acc[n][r0 + 1], 0.f));
                    unsigned P1 = pkbf(fmaxf(acc[n][r1], 0.f), fmaxf(acc[n][r1 + 1], 0.f));
                    auto r = __builtin_amdgcn_permlane32_swap(P1, P0, false, false);
                    B1[2 * m + t][n][c] = r[1];
                    B1[2 * m + t][n][2 + c] = r[0];
                }
        }
    }

    unsigned B2[4][2][4];
#pragma unroll
    for (int m = 0; m < 2; ++m) {
        f32x16 acc[2];
#pragma unroll
        for (int cc = 0; cc < 4; ++cc) {
            float4 bq = b1c[(m * 2 + q5) * 4 + cc];
#pragma unroll
            for (int n = 0; n < 2; ++n) {
                acc[n][4 * cc + 0] = bq.x;
                acc[n][4 * cc + 1] = bq.y;
                acc[n][4 * cc + 2] = bq.z;
                acc[n][4 * cc + 3] = bq.w;
            }
        }
#pragma unroll
        for (int ks = 0; ks < 4; ++ks) {
            bf16x8 af = A1[(m * 4 + ks) * 64 + lane];
#pragma unroll
            for (int n = 0; n < 2; ++n)
                acc[n] = __builtin_amdgcn_mfma_f32_32x32x16_bf16(
                    af, mkfrag(B1[ks][n][0], B1[ks][n][1], B1[ks][n][2], B1[ks][n][3]),
                    acc[n], 0, 0, 0);
        }
#pragma unroll
        for (int t = 0; t < 2; ++t) {
#pragma unroll
            for (int n = 0; n < 2; ++n)
#pragma unroll
                for (int c = 0; c < 2; ++c) {
                    int r0 = 2 * c + 8 * t;
                    int r1 = 2 * c + 8 * t + 4;
                    unsigned P0 = pkbf(fmaxf(acc[n][r0], 0.f), fmaxf(acc[n][r0 + 1], 0.f));
                    unsigned P1 = pkbf(fmaxf(acc[n][r1], 0.f), fmaxf(acc[n][r1 + 1], 0.f));
                    auto r = __builtin_amdgcn_permlane32_swap(P1, P0, false, false);
                    B2[2 * m + t][n][c] = r[1];
                    B2[2 * m + t][n][2 + c] = r[0];
                }
        }
    }

#pragma unroll
    for (int n = 0; n < 2; ++n)
#pragma unroll
        for (int r = 0; r < 16; ++r) acc2[n][r] = (r < 4) ? b2[r] : 0.f;
#pragma unroll
    for (int ks = 0; ks < 4; ++ks) {
        bf16x8 af = A2[ks * 64 + lane];
#pragma unroll
        for (int n = 0; n < 2; ++n)
            acc2[n] = __builtin_amdgcn_mfma_f32_32x32x16_bf16(
                af, mkfrag(B2[ks][n][0], B2[ks][n][1], B2[ks][n][2], B2[ks][n][3]),
                acc2[n], 0, 0, 0);
    }
}

// ---------- main sorted kernel: NT scatter store, (256,4) occupancy (R17-verified) ----------
__global__ __launch_bounds__(256, 4)
void colornet_sorted(const float2* __restrict__ pts,
                     const unsigned* __restrict__ perm,
                     const f32x2* __restrict__ g0, const f32x2* __restrict__ g1,
                     const f32x2* __restrict__ g2, const f32x2* __restrict__ g3,
                     const f32x2* __restrict__ g4, const f32x2* __restrict__ g5,
                     const float* __restrict__ ws,
                     const float* __restrict__ b2,
                     f32x4* __restrict__ out)
{
    const int lane = threadIdx.x & 63;
    const int wave = threadIdx.x >> 6;
    const int q5 = lane >> 5;
    int bid = blockIdx.x;
    int cpx = gridDim.x >> 3;
    bid = (bid & 7) * cpx + (bid >> 3);     // XCD-chunk swizzle (grid % 8 == 0)
    const int base_pt = bid * 256 + wave * 64;
    const char* wsb = (const char*)ws;

    float2 c = pts[base_pt + lane];
    float uA = fminf(fmaxf(c.x, 0.f), 1.f - 1e-6f);
    float vA = fminf(fmaxf(c.y, 0.f), 1.f - 1e-6f);

#define ADDR(IDX, R) int gx##IDX; float lu##IDX, lv##IDX; \
    { float fu_ = uA * (float)((R) - 1), fv_ = vA * (float)((R) - 1); \
      int i0_ = (int)floorf(fu_), j0_ = (int)floorf(fv_); \
      i0_ = i0_ < 0 ? 0 : (i0_ > (R) - 2 ? (R) - 2 : i0_); \
      j0_ = j0_ < 0 ? 0 : (j0_ > (R) - 2 ? (R) - 2 : j0_); \
      lu##IDX = fu_ - (float)i0_; lv##IDX = fv_ - (float)j0_; \
      gx##IDX = i0_ + j0_ * (R); }
    ADDR(7, 2048) ADDR(6, 1024) ADDR(5, 512) ADDR(4, 256)
    ADDR(3, 128)  ADDR(2, 64)   ADDR(1, 32)  ADDR(0, 16)

    const unsigned* G7 = (const unsigned*)(wsb + G7B_OFF);
    const unsigned* G6 = (const unsigned*)(wsb + G6B_OFF);
    unsigned t7_0 = G7[gx7], t7_1 = G7[gx7 + 1], t7_2 = G7[gx7 + 2048], t7_3 = G7[gx7 + 2049];
    unsigned t6_0 = G6[gx6], t6_1 = G6[gx6 + 1], t6_2 = G6[gx6 + 1024], t6_3 = G6[gx6 + 1025];

#define LOADF(IDX, R, G) \
    f32x2 f##IDX##_0 = (G)[gx##IDX],       f##IDX##_1 = (G)[gx##IDX + 1], \
          f##IDX##_2 = (G)[gx##IDX + (R)], f##IDX##_3 = (G)[gx##IDX + (R) + 1];
    LOADF(5, 512, g5) LOADF(4, 256, g4) LOADF(3, 128, g3)
    LOADF(2, 64,  g2) LOADF(1, 32,  g1) LOADF(0, 16,  g0)

    float lu_pe, lv_pe;
    int lc;
    {
        float fu = uA * 128.f, fv = vA * 128.f;
        int i0 = (int)floorf(fu);
        int j0 = (int)floorf(fv);
        i0 = i0 < 0 ? 0 : (i0 > 127 ? 127 : i0);
        j0 = j0 < 0 ? 0 : (j0 > 127 ? 127 : j0);
        lu_pe = fu - (float)i0;
        lv_pe = fv - (float)j0;
        lc = (i0 + j0 * 129) * 3;
    }
    const u32x4* LP = (const u32x4*)(wsb + LPE_OFF);
    u32x4 L00a = LP[lc],       L00b = LP[lc + 1],   L00c = LP[lc + 2];
    u32x4 L10a = LP[lc + 3],   L10b = LP[lc + 4],   L10c = LP[lc + 5];
    u32x4 L01a = LP[lc + 387], L01b = LP[lc + 388], L01c = LP[lc + 389];
    u32x4 L11a = LP[lc + 390], L11b = LP[lc + 391], L11c = LP[lc + 392];

    float pe[16];
#pragma unroll
    for (int kf = 0; kf < NF; ++kf) {
        float au = lu_pe * (float)(1 << kf);
        float av = lv_pe * (float)(1 << kf);
        float fu_ = __builtin_amdgcn_fractf(au);
        float fv_ = __builtin_amdgcn_fractf(av);
        pe[kf]          = __builtin_amdgcn_cosf(fu_);
        pe[NF + kf]     = __builtin_amdgcn_sinf(fu_);
        pe[2 * NF + kf] = __builtin_amdgcn_cosf(fv_);
        pe[3 * NF + kf] = __builtin_amdgcn_sinf(fv_);
    }

    f32x2 eA = { 0.f, 0.f };
#define WGT(IDX) float omu##IDX = 1.f - lu##IDX, omv##IDX = 1.f - lv##IDX; \
    float w00##IDX = omu##IDX * omv##IDX, w10##IDX = lu##IDX * omv##IDX, \
          w01##IDX = omu##IDX * lv##IDX,  w11##IDX = lu##IDX * lv##IDX;
    { WGT(7)
      eA += bf2(t7_0) * w007 + bf2(t7_1) * w107 + bf2(t7_2) * w017 + bf2(t7_3) * w117; }
    { WGT(6)
      eA += bf2(t6_0) * w006 + bf2(t6_1) * w106 + bf2(t6_2) * w016 + bf2(t6_3) * w116; }
#define SUMF(IDX) { WGT(IDX) \
      eA += f##IDX##_0 * w00##IDX + f##IDX##_1 * w10##IDX + f##IDX##_2 * w01##IDX + f##IDX##_3 * w11##IDX; }
    SUMF(5) SUMF(4) SUMF(3) SUMF(2) SUMF(1) SUMF(0)

    f32x2 cf[12];
    {
        float omu = 1.f - lu_pe, omv = 1.f - lv_pe;
        float q00 = omu * omv, q10 = lu_pe * omv, q01 = omu * lv_pe, q11 = lu_pe * lv_pe;
#define LPW2(W, A, B, C, Dd) \
        cf[W] = bf2(A) * q00 + bf2(B) * q10 + bf2(C) * q01 + bf2(Dd) * q11;
        LPW2(0,  L00a[0], L10a[0], L01a[0], L11a[0])
        LPW2(1,  L00a[1], L10a[1], L01a[1], L11a[1])
        LPW2(2,  L00a[2], L10a[2], L01a[2], L11a[2])
        LPW2(3,  L00a[3], L10a[3], L01a[3], L11a[3])
        LPW2(4,  L00b[0], L10b[0], L01b[0], L11b[0])
        LPW2(5,  L00b[1], L10b[1], L01b[1], L11b[1])
        LPW2(6,  L00b[2], L10b[2], L01b[2], L11b[2])
        LPW2(7,  L00b[3], L10b[3], L01b[3], L11b[3])
        LPW2(8,  L00c[0], L10c[0], L01c[0], L11c[0])
        LPW2(9,  L00c[1], L10c[1], L01c[1], L11c[1])
        LPW2(10, L00c[2], L10c[2], L01c[2], L11c[2])
        LPW2(11, L00c[3], L10c[3], L01c[3], L11c[3])
#undef LPW2
    }

    unsigned fdA[16];
    fdA[0] = pkbf(eA[0], eA[1]);
#pragma unroll
    for (int i = 0; i < 4; ++i) fdA[1 + i] = pkbf(cf[i][0], cf[i][1]);
#pragma unroll
    for (int i = 0; i < 8; ++i) {
        f32x2 g = { pe[2 * i], pe[2 * i + 1] };
        f32x2 m = cf[4 + i] * g;
        fdA[5 + i] = pkbf(m[0], m[1]);
    }
    fdA[13] = 0u; fdA[14] = 0u; fdA[15] = 0u;

    unsigned B0a[2][2][4];
#pragma unroll
    for (int ks = 0; ks < 2; ++ks)
#pragma unroll
        for (int j2 = 0; j2 < 4; ++j2) {
            unsigned a = fdA[8 * ks + j2];
            unsigned b = fdA[8 * ks + 4 + j2];
            auto r = __builtin_amdgcn_permlane32_swap(b, a, false, false);
            B0a[ks][1][j2] = r[0];
            B0a[ks][0][j2] = r[1];
        }

    f32x16 acc2[2];
    mlp_pair(B0a, ws, b2, lane, q5, acc2);

    if (lane < 32) {
#pragma unroll
        for (int n = 0; n < 2; ++n) {
            f32x4 o;
            o[0] = 1.f / (1.f + __expf(-acc2[n][0]));
            o[1] = 1.f / (1.f + __expf(-acc2[n][1]));
            o[2] = 1.f / (1.f + __expf(-acc2[n][2]));
            o[3] = 1.f / (1.f + __expf(-acc2[n][3]));
            int oi = (int)perm[base_pt + 32 * n + lane];
            __builtin_nontemporal_store(o, out + oi);   // NT: best for random 16B scatter (R15 A/B)
        }
    }
}

// ---------- fp32 unsorted fallback (R6..R18-verified) ----------
template<int R>
__device__ __forceinline__ void gather_level(const float* __restrict__ g,
                                             float u, float v,
                                             float& e0, float& e1) {
    const float scale = (float)(R - 1);
    float fu = u * scale, fv = v * scale;
    int i0 = (int)floorf(fu);
    int j0 = (int)floorf(fv);
    i0 = i0 < 0 ? 0 : (i0 > R - 2 ? R - 2 : i0);
    j0 = j0 < 0 ? 0 : (j0 > R - 2 ? R - 2 : j0);
    float lu = fu - (float)i0;
    float lv = fv - (float)j0;
    const float2* gg = (const float2*)g;
    int base = i0 + j0 * R;
    float2 f00 = gg[base];
    float2 f10 = gg[base + 1];
    float2 f01 = gg[base + R];
    float2 f11 = gg[base + R + 1];
    float omu = 1.f - lu, omv = 1.f - lv;
    float w00 = omu * omv, w10 = lu * omv, w01 = omu * lv, w11 = lu * lv;
    e0 += f00.x * w00 + f10.x * w10 + f01.x * w01 + f11.x * w11;
    e1 += f00.y * w00 + f10.y * w10 + f01.y * w01 + f11.y * w11;
}

__global__ __launch_bounds__(256, 4)
void colornet_fp32(const float* __restrict__ coords,
                   const float* __restrict__ g0, const float* __restrict__ g1,
                   const float* __restrict__ g2, const float* __restrict__ g3,
                   const float* __restrict__ g4, const float* __restrict__ g5,
                   const float* __restrict__ g6, const float* __restrict__ g7,
                   const float* __restrict__ lpe,
                   const float* __restrict__ ws,
                   const float* __restrict__ b2,
                   f32x4* __restrict__ out)
{
    const int lane = threadIdx.x & 63;
    const int wave = threadIdx.x >> 6;
    const int q5 = lane >> 5;
    const int base_pt = blockIdx.x * 256 + wave * 64;
    const int point = base_pt + lane;

    const float* cp = coords + 2 * point;
    float cx = __builtin_nontemporal_load(cp);
    float cy = __builtin_nontemporal_load(cp + 1);
    float uA = fminf(fmaxf(cx, 0.f), 1.f - 1e-6f);
    float vA = fminf(fmaxf(cy, 0.f), 1.f - 1e-6f);

    float e0 = 0.f, e1 = 0.f;
    gather_level<16>(g0, uA, vA, e0, e1);
    gather_level<32>(g1, uA, vA, e0, e1);
    gather_level<64>(g2, uA, vA, e0, e1);
    gather_level<128>(g3, uA, vA, e0, e1);
    gather_level<256>(g4, uA, vA, e0, e1);
    gather_level<512>(g5, uA, vA, e0, e1);
    gather_level<1024>(g6, uA, vA, e0, e1);
    gather_level<2048>(g7, uA, vA, e0, e1);

    float coeff[LPE_OUT];
    float lu_pe, lv_pe;
    {
        float fu = uA * 128.f, fv = vA * 128.f;
        int i0 = (int)floorf(fu);
        int j0 = (int)floorf(fv);
        i0 = i0 < 0 ? 0 : (i0 > 127 ? 127 : i0);
        j0 = j0 < 0 ? 0 : (j0 > 127 ? 127 : j0);
        lu_pe = fu - (float)i0;
        lv_pe = fv - (float)j0;
        int base = (i0 + j0 * 129) * LPE_OUT;
        const float4* p00 = (const float4*)(lpe + base);
        const float4* p10 = (const float4*)(lpe + base + LPE_OUT);
        const float4* p01 = (const float4*)(lpe + base + 129 * LPE_OUT);
        const float4* p11 = (const float4*)(lpe + base + 130 * LPE_OUT);
        float omu = 1.f - lu_pe, omv = 1.f - lv_pe;
        float w00 = omu * omv, w10 = lu_pe * omv, w01 = omu * lv_pe, w11 = lu_pe * lv_pe;
#pragma unroll
        for (int q = 0; q < 6; ++q) {
            float4 a = p00[q], bq = p10[q], cq = p01[q], dq = p11[q];
            coeff[4 * q + 0] = a.x * w00 + bq.x * w10 + cq.x * w01 + dq.x * w11;
            coeff[4 * q + 1] = a.y * w00 + bq.y * w10 + cq.y * w01 + dq.y * w11;
            coeff[4 * q + 2] = a.z * w00 + bq.z * w10 + cq.z * w01 + dq.z * w11;
            coeff[4 * q + 3] = a.w * w00 + bq.w * w10 + cq.w * w01 + dq.w * w11;
        }
    }

    float pe[16];
#pragma unroll
    for (int kf = 0; kf < NF; ++kf) {
        const float fr = 6.28318530717958647692f * (float)(1 << kf);
        float au = lu_pe * fr;
        float av = lv_pe * fr;
        pe[kf]          = __cosf(au);
        pe[NF + kf]     = __sinf(au);
        pe[2 * NF + kf] = __cosf(av);
        pe[3 * NF + kf] = __sinf(av);
    }

    float feat[32];
    feat[0] = e0; feat[1] = e1;
#pragma unroll
    for (int q = 0; q < D0; ++q) feat[2 + q] = coeff[q];
#pragma unroll
    for (int q = 0; q < 4 * NF; ++q) feat[2 + D0 + q] = coeff[D0 + q] * pe[q];
#pragma unroll
    for (int q = 26; q < 32; ++q) feat[q] = 0.f;

    unsigned fd[16];
#pragma unroll
    for (int i = 0; i < 16; ++i) fd[i] = pkbf(feat[2 * i], feat[2 * i + 1]);

    unsigned B0[2][2][4];
#pragma unroll
    for (int ks = 0; ks < 2; ++ks)
#pragma unroll
        for (int j2 = 0; j2 < 4; ++j2) {
            unsigned a = fd[8 * ks + j2];
            unsigned b = fd[8 * ks + 4 + j2];
            auto r = __builtin_amdgcn_permlane32_swap(b, a, false, false);
            B0[ks][1][j2] = r[0];
            B0[ks][0][j2] = r[1];
        }

    f32x16 acc2[2];
    mlp_pair(B0, ws, b2, lane, q5, acc2);
    if (lane < 32) {
#pragma unroll
        for (int n = 0; n < 2; ++n) {
            f32x4 o;
            o[0] = 1.f / (1.f + __expf(-acc2[n][0]));
            o[1] = 1.f / (1.f + __expf(-acc2[n][1]));
            o[2] = 1.f / (1.f + __expf(-acc2[n][2]));
            o[3] = 1.f / (1.f + __expf(-acc2[n][3]));
            __builtin_nontemporal_store(o, out + (base_pt + 32 * n + lane));
        }
    }
}

extern "C" void kernel_launch(void* const* d_in, const int* in_sizes, int n_in,
                              void* d_out, int out_size, void* d_ws, size_t ws_size,
                              hipStream_t stream) {
    const float* coords = (const float*)d_in[0];
    const float* g0 = (const float*)d_in[1];
    const float* g1 = (const float*)d_in[2];
    const float* g2 = (const float*)d_in[3];
    const float* g3 = (const float*)d_in[4];
    const float* g4 = (const float*)d_in[5];
    const float* g5 = (const float*)d_in[6];
    const float* g6 = (const float*)d_in[7];
    const float* g7 = (const float*)d_in[8];
    const float* lpe = (const float*)d_in[9];
    const float* w0 = (const float*)d_in[10];
    const float* b0 = (const float*)d_in[11];
    const float* w1 = (const float*)d_in[12];
    const float* b1 = (const float*)d_in[13];
    const float* w2 = (const float*)d_in[14];
    const float* b2 = (const float*)d_in[15];
    f32x4* out = (f32x4*)d_out;

    int B = in_sizes[0] / 2;
    char* wsb = (char*)d_ws;

    if (ws_size >= WS_NEED && B == 1048576) {
        unsigned* totals = (unsigned*)(wsb + TOTC_OFF);
        unsigned* cursor = totals + NBUCKET;
        float2*   scoord = (float2*)(wsb + SCOORD_OFF);
        unsigned* perm   = (unsigned*)(wsb + PERM_OFF);
        const float2* c2 = (const float2*)coords;

        (void)hipMemsetAsync(totals, 0, 2 * NBUCKET * sizeof(unsigned), stream);
        fused_pre<<<10949, 256, 0, stream>>>((const float4*)g6, (const float4*)g7,
                                             (const float4*)lpe, c2, totals,
                                             w0, b0, w1, b1, w2, (float*)d_ws, wsb);
        sort_scatter<<<NROWS, 256, 0, stream>>>(c2, totals, cursor, scoord, perm);

        colornet_sorted<<<4096, 256, 0, stream>>>(scoord, perm,
                                                  (const f32x2*)g0, (const f32x2*)g1,
                                                  (const f32x2*)g2, (const f32x2*)g3,
                                                  (const f32x2*)g4, (const f32x2*)g5,
                                                  (const float*)d_ws, b2, out);
    } else {
        prep_kernel<<<1, 256, 0, stream>>>(w0, b0, w1, b1, w2, (float*)d_ws);
        colornet_fp32<<<B / 256, 256, 0, stream>>>(coords, g0, g1, g2, g3, g4, g5, g6, g7,
                                                   lpe, (const float*)d_ws, b2, out);
    }
}